// Round 1
// baseline (212.583 us; speedup 1.0000x reference)
//
#include <hip/hip_runtime.h>

// ---------------------------------------------------------------------------
// ConvQuantizationWrapper: exact integer reformulation.
// out = [conv3x3(q_in, tc(q_w)) + zp*conv3x3(ones, q_w)] / (sa*sw) + bias
//   q_in = clip(round(x*sa - zp), 0, 255)            (u8)
//   q_w  = round(w*sw);  tc(q_w) = int8 of (q_w+256)&255
// We store qa = q_in - 128 (signed i8) and correct with +128*conv(ones, tc(q_w)).
// conv(ones, .) terms depend only on (o, row-border-case, col-border-case):
// precomputed as 64x9 channel-summed tap tables (tc and raw variants).
// ---------------------------------------------------------------------------

#if defined(__has_builtin)
#if __has_builtin(__builtin_amdgcn_sdot4)
#define HAVE_SDOT4 1
#endif
#endif

static __device__ __forceinline__ int dot4(int a, int b, int c) {
#ifdef HAVE_SDOT4
  return __builtin_amdgcn_sdot4(a, b, c, false);
#else
  return c + ((a << 24) >> 24) * ((b << 24) >> 24)
           + ((a << 16) >> 24) * ((b << 16) >> 24)
           + ((a << 8) >> 24) * ((b << 8) >> 24)
           + (a >> 24) * (b >> 24);
#endif
}

// ---- prep 1: quantize weights -> i8, layout [o][tap][c] ----
__global__ void prep_w(const float* __restrict__ wt, const float* __restrict__ sw_p,
                       signed char* __restrict__ w8) {
  int t = blockIdx.x * 256 + threadIdx.x;   // 36864 total
  if (t >= 36864) return;
  float sw = sw_p[0];
  int o = t / 576;
  int rem = t - o * 576;
  int k = rem >> 6;        // tap 0..8
  int i = rem & 63;        // input channel
  float wv = wt[(o * 64 + i) * 9 + k];      // OIHW flat
  int q = (int)rintf(wv * sw);
  w8[(o * 9 + k) * 64 + i] = (signed char)(q & 255);  // two's-complement wrap
}

// ---- prep 2: per-(o,tap) channel sums, tc and raw variants ----
__global__ void prep_q(const float* __restrict__ wt, const float* __restrict__ sw_p,
                       const signed char* __restrict__ w8,
                       int* __restrict__ Qtc, int* __restrict__ Qraw) {
  int t = blockIdx.x * 64 + threadIdx.x;    // 576 total
  if (t >= 576) return;
  int o = t / 9, k = t - o * 9;
  float sw = sw_p[0];
  int stc = 0, srw = 0;
  for (int i = 0; i < 64; ++i) {
    stc += (int)w8[(o * 9 + k) * 64 + i];
    srw += (int)rintf(wt[(o * 64 + i) * 9 + k] * sw);
  }
  Qtc[t] = stc;
  Qraw[t] = srw;
}

// ---- quantize activations: NCHW fp32 -> NHWC i8 (q_in - 128) ----
__global__ __launch_bounds__(256) void quant_a(const float* __restrict__ x,
                                               const float* __restrict__ sa_p,
                                               const float* __restrict__ zp_p,
                                               signed char* __restrict__ qa) {
  const int h = blockIdx.x;                 // 0..55
  const int n = blockIdx.y;                 // 0..63
  const int t = threadIdx.x;
  const int w = t & 63;                     // pixel col (lanes 56..63 idle)
  const int cq = t >> 6;                    // channel quarter 0..3
  if (w >= 56) return;
  const float sa = sa_p[0], zp = zp_p[0];
  const float* xb = x + ((size_t)(n * 64) * 56 + h) * 56 + w;  // + c*3136
  unsigned int pk[4] = {0u, 0u, 0u, 0u};
#pragma unroll
  for (int i = 0; i < 16; ++i) {
    int c = cq * 16 + i;
    float v = xb[c * 3136];
    float tq;
    {
#pragma clang fp contract(off)
      tq = v * sa - zp;                     // match ref: mul then sub, no fma
    }
    float q = rintf(tq);                    // round half-to-even, like jnp.round
    q = fminf(fmaxf(q, 0.0f), 255.0f);
    int iq = (int)q - 128;                  // shift into signed i8 range
    pk[i >> 2] |= ((unsigned)(iq & 255)) << ((i & 3) * 8);
  }
  ((int4*)(qa + ((size_t)((n * 56 + h) * 56 + w)) * 64))[cq] =
      make_int4(pk[0], pk[1], pk[2], pk[3]);
}

// ---- main conv: wave = one output row, lane = output channel ----
static __device__ __forceinline__ void tap(int& acc, const int4* ab, int col,
                                           const int4& w0, const int4& w1,
                                           const int4& w2, const int4& w3) {
  const int4 a0 = ab[col * 4 + 0];
  const int4 a1 = ab[col * 4 + 1];
  const int4 a2 = ab[col * 4 + 2];
  const int4 a3 = ab[col * 4 + 3];
  acc = dot4(a0.x, w0.x, acc); acc = dot4(a0.y, w0.y, acc);
  acc = dot4(a0.z, w0.z, acc); acc = dot4(a0.w, w0.w, acc);
  acc = dot4(a1.x, w1.x, acc); acc = dot4(a1.y, w1.y, acc);
  acc = dot4(a1.z, w1.z, acc); acc = dot4(a1.w, w1.w, acc);
  acc = dot4(a2.x, w2.x, acc); acc = dot4(a2.y, w2.y, acc);
  acc = dot4(a2.z, w2.z, acc); acc = dot4(a2.w, w2.w, acc);
  acc = dot4(a3.x, w3.x, acc); acc = dot4(a3.y, w3.y, acc);
  acc = dot4(a3.z, w3.z, acc); acc = dot4(a3.w, w3.w, acc);
}

__global__ __launch_bounds__(256) void conv_main(
    const signed char* __restrict__ qa, const signed char* __restrict__ w8,
    const int* __restrict__ Qtc, const int* __restrict__ Qraw,
    const float* __restrict__ bias, const float* __restrict__ sa_p,
    const float* __restrict__ sw_p, const float* __restrict__ zp_p,
    float* __restrict__ out) {
  __shared__ int4 lds4[1344];               // 6 rows x 56 cols x 64 ch (21504 B)
  const int n = blockIdx.y;
  const int h0 = blockIdx.x * 4;
  const int tid = threadIdx.x;

  // stage rows h0-1 .. h0+4 (zero-fill out-of-range rows)
  for (int u = tid; u < 1344; u += 256) {
    const int r = u / 224;                  // 224 int4 per row
    const int j = u - r * 224;
    const int gh = h0 - 1 + r;
    int4 v = make_int4(0, 0, 0, 0);
    if ((unsigned)gh < 56u)
      v = ((const int4*)(qa + (size_t)(n * 56 + gh) * 3584))[j];
    lds4[u] = v;
  }
  __syncthreads();

  const int wid = tid >> 6;                 // wave id -> row
  const int o = tid & 63;                   // lane -> output channel
  const int h = h0 + wid;

  // border-aware conv(ones, .) sums for this (o, h)
  int ctc[3] = {0, 0, 0}, crw[3] = {0, 0, 0};
#pragma unroll
  for (int kh = 0; kh < 3; ++kh) {
    if ((unsigned)(h + kh - 1) < 56u) {
#pragma unroll
      for (int kw = 0; kw < 3; ++kw) {
        ctc[kw] += Qtc[o * 9 + kh * 3 + kw];
        crw[kw] += Qraw[o * 9 + kh * 3 + kw];
      }
    }
  }
  const float sa = sa_p[0], sw = sw_p[0], zp = zp_p[0];
  const float rden = 1.0f / (sw * sa);
  const float bo = bias[o];
  const int Stm = ctc[0] + ctc[1] + ctc[2];
  const int Srm = crw[0] + crw[1] + crw[2];
  const float corr_m = 128.0f * (float)Stm + zp * (float)Srm;
  const float corr_l = 128.0f * (float)(Stm - ctc[0]) + zp * (float)(Srm - crw[0]);
  const float corr_r = 128.0f * (float)(Stm - ctc[2]) + zp * (float)(Srm - crw[2]);
  float* const orow = out + (size_t)((n * 64 + o) * 56 + h) * 56;

#pragma unroll 1
  for (int pt = 0; pt < 4; ++pt) {          // 4 pixel tiles of 14
    int acc[14];
#pragma unroll
    for (int i = 0; i < 14; ++i) acc[i] = 0;
#pragma unroll
    for (int k = 0; k < 9; ++k) {
      const int kh = k / 3, kw = k - 3 * (k / 3);
      const int4* wp = (const int4*)(w8 + (o * 9 + k) * 64);
      const int4 w0 = wp[0], w1 = wp[1], w2 = wp[2], w3 = wp[3];
      const int4* ab = lds4 + (wid + kh) * 224;
#pragma unroll
      for (int pi = 0; pi < 14; ++pi) {
        const int col = pt * 14 + pi + kw - 1;
        if (kw == 0 && pi == 0) {
          if (pt > 0) tap(acc[pi], ab, col, w0, w1, w2, w3);
        } else if (kw == 2 && pi == 13) {
          if (pt < 3) tap(acc[pi], ab, col, w0, w1, w2, w3);
        } else {
          tap(acc[pi], ab, col, w0, w1, w2, w3);
        }
      }
    }
#pragma unroll
    for (int pi = 0; pi < 14; ++pi) {
      const int p = pt * 14 + pi;
      const float corr = (p == 0) ? corr_l : ((p == 55) ? corr_r : corr_m);
      orow[p] = ((float)acc[pi] + corr) * rden + bo;
    }
  }
}

extern "C" void kernel_launch(void* const* d_in, const int* in_sizes, int n_in,
                              void* d_out, int out_size, void* d_ws, size_t ws_size,
                              hipStream_t stream) {
  const float* x    = (const float*)d_in[0];
  const float* wt   = (const float*)d_in[1];
  const float* bias = (const float*)d_in[2];
  const float* sa   = (const float*)d_in[3];
  const float* sw   = (const float*)d_in[4];
  const float* zp   = (const float*)d_in[5];
  float* out = (float*)d_out;

  char* ws = (char*)d_ws;
  signed char* qa = (signed char*)ws;                       // 12,845,056 B
  signed char* w8 = (signed char*)(ws + 12845056);          // 36,864 B
  int* Qtc = (int*)(ws + 12881920);                         // 2,304 B
  int* Qraw = (int*)(ws + 12884224);                        // 2,304 B

  prep_w<<<144, 256, 0, stream>>>(wt, sw, w8);
  prep_q<<<9, 64, 0, stream>>>(wt, sw, w8, Qtc, Qraw);
  quant_a<<<dim3(56, 64), 256, 0, stream>>>(x, sa, zp, qa);
  conv_main<<<dim3(14, 64), 256, 0, stream>>>(qa, w8, Qtc, Qraw, bias, sa, sw, zp, out);
}

// Round 2
// 143.348 us; speedup vs baseline: 1.4830x; 1.4830x over previous
//
#include <hip/hip_runtime.h>

// ---------------------------------------------------------------------------
// ConvQuantizationWrapper: exact integer reformulation, MFMA i8 version.
// out = [conv3x3(q_in, tc(q_w)) + zp*conv3x3(ones, q_w)] / (sa*sw) + bias
//   q_in = clip(round(x*sa - zp), 0, 255)            (u8)
//   q_w  = round(w*sw);  tc(q_w) = int8 of (q_w+256)&255
// qa stores (q_in - 128) as signed i8 in zero-PADDED NHWC [n][58][58][64c];
// pad bytes are 0, and border-aware correction tables (as in R1, verified)
// add back 128*sum(tc weights over in-range taps) + zp*sum(raw weights).
// Conv is implicit GEMM on v_mfma_i32_32x32x32_i8:
//   M=32 pixels, N=32 out-channels, K=32 in-channels; 9 taps x 2 K-halves.
// ---------------------------------------------------------------------------

typedef int v4i  __attribute__((ext_vector_type(4)));
typedef int v16i __attribute__((ext_vector_type(16)));

// qa padded geometry
#define QA_ROW   3712        // 58 cols * 64 B
#define QA_IMG   215296      // 58 rows * QA_ROW
#define QA_BYTES 13778944    // 64 images

// ---- prep 1: quantize weights -> i8, layout [o][tap][c] ----
__global__ void prep_w(const float* __restrict__ wt, const float* __restrict__ sw_p,
                       signed char* __restrict__ w8) {
  int t = blockIdx.x * 256 + threadIdx.x;   // 36864 total
  if (t >= 36864) return;
  float sw = sw_p[0];
  int o = t / 576;
  int rem = t - o * 576;
  int k = rem >> 6;        // tap 0..8
  int i = rem & 63;        // input channel
  float wv = wt[(o * 64 + i) * 9 + k];      // OIHW flat
  int q = (int)rintf(wv * sw);
  w8[(o * 9 + k) * 64 + i] = (signed char)(q & 255);  // two's-complement wrap
}

// ---- prep 2: per-(o,tap) channel sums, tc and raw variants ----
__global__ void prep_q(const float* __restrict__ wt, const float* __restrict__ sw_p,
                       const signed char* __restrict__ w8,
                       int* __restrict__ Qtc, int* __restrict__ Qraw) {
  int t = blockIdx.x * 64 + threadIdx.x;    // 576 total
  if (t >= 576) return;
  int o = t / 9, k = t - o * 9;
  float sw = sw_p[0];
  int stc = 0, srw = 0;
  for (int i = 0; i < 64; ++i) {
    stc += (int)w8[(o * 9 + k) * 64 + i];
    srw += (int)rintf(wt[(o * 64 + i) * 9 + k] * sw);
  }
  Qtc[t] = stc;
  Qraw[t] = srw;
}

// ---- quantize activations: NCHW fp32 -> padded NHWC i8 (q_in - 128) ----
__global__ __launch_bounds__(256) void quant_a(const float* __restrict__ x,
                                               const float* __restrict__ sa_p,
                                               const float* __restrict__ zp_p,
                                               signed char* __restrict__ qa) {
  __shared__ unsigned int lds[56 * 17];     // [w][cq] dword, stride 17 (odd: no conflicts)
  const int h = blockIdx.x;                 // 0..55
  const int n = blockIdx.y;                 // 0..63
  const int t = threadIdx.x;
  const float sa = sa_p[0], zp = zp_p[0];
  const float* xb = x + (size_t)n * 64 * 3136 + h * 56;

  // phase 1: load + quantize + pack 4 channels per dword, store to LDS [w][cq]
#pragma unroll
  for (int it = 0; it < 4; ++it) {
    int idx = t + 256 * it;                 // 896 tasks
    if (idx < 896) {
      int w = idx % 56;
      int cq = idx / 56;                    // 0..15
      unsigned pk = 0;
#pragma unroll
      for (int e = 0; e < 4; ++e) {
        int c = 4 * cq + e;
        float v = xb[(size_t)c * 3136 + w];
        float tq;
        {
#pragma clang fp contract(off)
          tq = v * sa - zp;                 // match ref: mul then sub, no fma
        }
        float q = rintf(tq);                // half-to-even, like jnp.round
        q = fminf(fmaxf(q, 0.0f), 255.0f);
        int iq = (int)q - 128;              // shift into signed i8 range
        pk |= ((unsigned)(iq & 255)) << (8 * e);
      }
      lds[w * 17 + cq] = pk;
    }
  }
  __syncthreads();

  signed char* const qrow = qa + (size_t)n * QA_IMG + (size_t)(h + 1) * QA_ROW;
  if (t < 224) {
    // interior: 56 cols x 4 int4 each, fully coalesced 3584 B store
    int w = t >> 2, q2 = t & 3;
    uint4 v = make_uint4(lds[w * 17 + 4 * q2 + 0], lds[w * 17 + 4 * q2 + 1],
                         lds[w * 17 + 4 * q2 + 2], lds[w * 17 + 4 * q2 + 3]);
    ((uint4*)(qrow + (w + 1) * 64))[q2] = v;
  } else {
    int p = t - 224;
    if (p < 8) {                            // this row's col pads: col 0 and col 57
      signed char* dst = qrow + ((p < 4) ? 0 : 57 * 64);
      ((uint4*)dst)[p & 3] = make_uint4(0, 0, 0, 0);
    }
  }
  // full pad rows (top for h==0, bottom for h==55): 58*4 = 232 int4 of zeros
  if (h == 0) {
    uint4* pr = (uint4*)(qa + (size_t)n * QA_IMG);
    for (int idx = t; idx < 232; idx += 256) pr[idx] = make_uint4(0, 0, 0, 0);
  }
  if (h == 55) {
    uint4* pr = (uint4*)(qa + (size_t)n * QA_IMG + (size_t)57 * QA_ROW);
    for (int idx = t; idx < 232; idx += 256) pr[idx] = make_uint4(0, 0, 0, 0);
  }
}

// ---- main conv: implicit GEMM on v_mfma_i32_32x32x32_i8 ----
// wave = (n, h, og): M=32 px, N=32 och (og half), K accumulated 9 taps x 64 ch.
// Two pixel sub-tiles per row: px0=0 (store px<24) and px0=24 (store all 32).
__global__ __launch_bounds__(256, 3) void conv_mfma(
    const signed char* __restrict__ qa, const signed char* __restrict__ w8,
    const int* __restrict__ Qtc, const int* __restrict__ Qraw,
    const float* __restrict__ bias, const float* __restrict__ sa_p,
    const float* __restrict__ sw_p, const float* __restrict__ zp_p,
    float* __restrict__ out) {
  const int tid = threadIdx.x;
  const int lane = tid & 63;
  const int wv = tid >> 6;                  // 0..3
  const int n = blockIdx.y;
  const int h = blockIdx.x * 2 + (wv >> 1); // 0..55
  const int og = wv & 1;                    // och half
  const int ln = lane & 31;
  const int lhi = lane >> 5;                // 0/1 -> K sub-half / row offset
  const int o = og * 32 + ln;

  // B fragments: B[n=ln][k = lhi*16 + j] for each (tap, K-half kk)
  const signed char* wb = w8 + (size_t)o * 9 * 64 + lhi * 16;
  v4i B[9][2];
#pragma unroll
  for (int tp = 0; tp < 9; ++tp)
#pragma unroll
    for (int kk = 0; kk < 2; ++kk)
      B[tp][kk] = *(const v4i*)(wb + tp * 64 + kk * 32);

  // border-aware conv(ones,.) correction sums for this (o, h)
  int ctc[3] = {0, 0, 0}, crw[3] = {0, 0, 0};
#pragma unroll
  for (int kh = 0; kh < 3; ++kh) {
    if ((unsigned)(h + kh - 1) < 56u) {
#pragma unroll
      for (int kw = 0; kw < 3; ++kw) {
        ctc[kw] += Qtc[o * 9 + kh * 3 + kw];
        crw[kw] += Qraw[o * 9 + kh * 3 + kw];
      }
    }
  }
  const float sa = sa_p[0], sw = sw_p[0], zp = zp_p[0];
  const float rden = 1.0f / (sw * sa);
  const float bo = bias[o];
  const int Stm = ctc[0] + ctc[1] + ctc[2];
  const int Srm = crw[0] + crw[1] + crw[2];
  const float corr_m = 128.0f * (float)Stm + zp * (float)Srm;
  const float corr_l = 128.0f * (float)(Stm - ctc[0]) + zp * (float)(Srm - crw[0]);
  const float corr_r = 128.0f * (float)(Stm - ctc[2]) + zp * (float)(Srm - crw[2]);

  // per-lane qa base: A[m=ln][k = kk*32 + lhi*16 + j]
  const signed char* qbase = qa + (size_t)n * QA_IMG + (size_t)h * QA_ROW + ln * 64 + lhi * 16;
  float* const orow = out + ((size_t)(n * 64 + o) * 56 + h) * 56;

#pragma unroll
  for (int st = 0; st < 2; ++st) {
    const int px0 = st * 24;
    v16i acc = {0, 0, 0, 0, 0, 0, 0, 0, 0, 0, 0, 0, 0, 0, 0, 0};
#pragma unroll
    for (int kh = 0; kh < 3; ++kh) {
#pragma unroll
      for (int kw = 0; kw < 3; ++kw) {
        const signed char* ap = qbase + kh * QA_ROW + (px0 + kw) * 64;
        v4i a0 = *(const v4i*)(ap);         // K-half 0 (ch 0..31)
        v4i a1 = *(const v4i*)(ap + 32);    // K-half 1 (ch 32..63)
        acc = __builtin_amdgcn_mfma_i32_32x32x32_i8(a0, B[kh * 3 + kw][0], acc, 0, 0, 0);
        acc = __builtin_amdgcn_mfma_i32_32x32x32_i8(a1, B[kh * 3 + kw][1], acc, 0, 0, 0);
      }
    }
    // epilogue: C/D layout col(=och)=lane&31, row(=px) = (r&3) + 8*(r>>2) + 4*lhi
#pragma unroll
    for (int q = 0; q < 4; ++q) {
      const int pxb = px0 + 8 * q + 4 * lhi;
      if (st == 0 && pxb >= 24) continue;   // overlap written by st==1
      float4 vv;
      float tmp[4];
#pragma unroll
      for (int e = 0; e < 4; ++e) {
        const int px = pxb + e;
        const float corr = (px == 0) ? corr_l : ((px == 55) ? corr_r : corr_m);
        tmp[e] = ((float)acc[4 * q + e] + corr) * rden + bo;
      }
      vv.x = tmp[0]; vv.y = tmp[1]; vv.z = tmp[2]; vv.w = tmp[3];
      *(float4*)(orow + pxb) = vv;
    }
  }
}

extern "C" void kernel_launch(void* const* d_in, const int* in_sizes, int n_in,
                              void* d_out, int out_size, void* d_ws, size_t ws_size,
                              hipStream_t stream) {
  const float* x    = (const float*)d_in[0];
  const float* wt   = (const float*)d_in[1];
  const float* bias = (const float*)d_in[2];
  const float* sa   = (const float*)d_in[3];
  const float* sw   = (const float*)d_in[4];
  const float* zp   = (const float*)d_in[5];
  float* out = (float*)d_out;

  char* ws = (char*)d_ws;
  signed char* qa = (signed char*)ws;                       // QA_BYTES
  signed char* w8 = (signed char*)(ws + QA_BYTES);          // 36,864 B
  int* Qtc  = (int*)(ws + QA_BYTES + 36864);                // 2,304 B
  int* Qraw = (int*)(ws + QA_BYTES + 36864 + 2304);         // 2,304 B

  prep_w<<<144, 256, 0, stream>>>(wt, sw, w8);
  prep_q<<<9, 64, 0, stream>>>(wt, sw, w8, Qtc, Qraw);
  quant_a<<<dim3(56, 64), 256, 0, stream>>>(x, sa, zp, qa);
  conv_mfma<<<dim3(28, 64), 256, 0, stream>>>(qa, w8, Qtc, Qraw, bias, sa, sw, zp, out);
}

// Round 3
// 140.560 us; speedup vs baseline: 1.5124x; 1.0198x over previous
//
#include <hip/hip_runtime.h>

// ---------------------------------------------------------------------------
// ConvQuantizationWrapper: exact integer reformulation, MFMA i8, pixel-linear.
// out = [conv3x3(q_in, tc(q_w)) + zp*conv3x3(ones, q_w)] / (sa*sw) + bias
//   q_in = clip(round(x*sa - zp), 0, 255) (u8);  q_w = round(w*sw)
// qa holds (q_in - 128) i8 in zero-padded NHWC [n][58][58][64c].
// conv: v_mfma_i32_32x32x32_i8, M = 32 flat pixels (px = h*56+w, crossing rows
// is fine: qa addressing is affine in (kh,kw), out is px-linear per (n,o)).
// Border correction per element via inclusion-exclusion over the per-(o,tap)
// channel-sum tables: corr = 128*sum_valid(Qtc) + zp*sum_valid(Qraw).
// ---------------------------------------------------------------------------

typedef int v4i  __attribute__((ext_vector_type(4)));
typedef int v16i __attribute__((ext_vector_type(16)));

#define QA_ROW   3712        // 58 cols * 64 B
#define QA_IMG   215296      // 58 rows * QA_ROW
#define QA_BYTES 13778944    // 64 images

// ---- fused weight prep: quantize + per-(o,tap) channel sums (wave reduce) ----
__global__ __launch_bounds__(64) void prep_wq(const float* __restrict__ wt,
                                              const float* __restrict__ sw_p,
                                              signed char* __restrict__ w8,
                                              int* __restrict__ Qtc,
                                              int* __restrict__ Qraw) {
  const int o = blockIdx.x;             // 0..63
  const int i = threadIdx.x;            // input channel 0..63
  const float sw = sw_p[0];
  const float* wp = wt + (size_t)(o * 64 + i) * 9;
  int q[9];
#pragma unroll
  for (int k = 0; k < 9; ++k) q[k] = (int)rintf(wp[k] * sw);
#pragma unroll
  for (int k = 0; k < 9; ++k)
    w8[(o * 9 + k) * 64 + i] = (signed char)(q[k] & 255);
#pragma unroll
  for (int k = 0; k < 9; ++k) {
    int stc = (int)(signed char)(q[k] & 255);   // two's-complement i8 value
    int srw = q[k];
#pragma unroll
    for (int off = 32; off; off >>= 1) {
      stc += __shfl_xor(stc, off);
      srw += __shfl_xor(srw, off);
    }
    if (i == 0) { Qtc[o * 9 + k] = stc; Qraw[o * 9 + k] = srw; }
  }
}

// ---- quantize activations: NCHW fp32 -> padded NHWC i8 (q_in - 128) ----
// 2 rows per block; float4 coalesced loads, LDS byte-transpose (stride 68).
__global__ __launch_bounds__(256) void quant_a(const float* __restrict__ x,
                                               const float* __restrict__ sa_p,
                                               const float* __restrict__ zp_p,
                                               signed char* __restrict__ qa) {
  __shared__ int ldsbuf[1904];          // 2 * 56 * 68 bytes
  signed char* lds = (signed char*)ldsbuf;
  const int bx = blockIdx.x;            // 0..27 -> rows 2bx, 2bx+1
  const int n = blockIdx.y;
  const int t = threadIdx.x;
  const float sa = sa_p[0], zp = zp_p[0];
  const float* xim = x + (size_t)n * 200704;    // 64 * 3136
  const int h0 = bx * 2;

#pragma unroll
  for (int it = 0; it < 7; ++it) {
    const int idx = t + 256 * it;       // 0..1791: [r][c][w4]
    const int r = idx >= 896;
    const int rem = idx - 896 * r;
    const int c = (rem * 2341) >> 15;   // rem / 14  (exact for rem < 896)
    const int w4 = rem - c * 14;
    const float4 v = *(const float4*)(xim + (size_t)c * 3136 + (h0 + r) * 56 + w4 * 4);
    signed char* dst = lds + r * 3808 + w4 * 272 + c;   // [(4*w4+e)*68 + c]
    const float vv[4] = {v.x, v.y, v.z, v.w};
#pragma unroll
    for (int e = 0; e < 4; ++e) {
      float tq;
      {
#pragma clang fp contract(off)
        tq = vv[e] * sa - zp;           // match ref: mul then sub, no fma
      }
      float qf = rintf(tq);             // half-to-even, like jnp.round
      qf = fminf(fmaxf(qf, 0.0f), 255.0f);
      dst[e * 68] = (signed char)((int)qf - 128);
    }
  }
  __syncthreads();

  signed char* const qim = qa + (size_t)n * QA_IMG;
#pragma unroll
  for (int it = 0; it < 2; ++it) {
    const int idx = t + 256 * it;
    if (idx < 448) {                    // interior: 2 rows x 56 cols x 16B quads
      const int r = idx >= 224;
      const int u = idx - 224 * r;
      const int w = u >> 2, q2 = u & 3;
      const unsigned* s = (const unsigned*)(lds + r * 3808 + w * 68 + q2 * 16);
      const uint4 vv = make_uint4(s[0], s[1], s[2], s[3]);
      *((uint4*)(qim + (size_t)(h0 + r + 1) * QA_ROW + (w + 1) * 64 + q2 * 16)) = vv;
    } else if (idx < 464) {             // col pads: col 0 and col 57, both rows
      const int p = idx - 448;
      const int r = p >> 3;
      const int side = (p >> 2) & 1;
      const int j = p & 3;
      *((uint4*)(qim + (size_t)(h0 + r + 1) * QA_ROW + side * 57 * 64 + j * 16)) =
          make_uint4(0, 0, 0, 0);
    }
  }
  if (bx == 0 && t < 232)               // top pad row
    ((uint4*)qim)[t] = make_uint4(0, 0, 0, 0);
  if (bx == 27 && t < 232)              // bottom pad row
    ((uint4*)(qim + (size_t)57 * QA_ROW))[t] = make_uint4(0, 0, 0, 0);
}

// ---- main conv: implicit GEMM, M = 32 flat pixels, N = 32 och, K = 9x64 ----
// block = 4 waves: (nsub 0/1) x (og 0/1); each wave: 2 sub-tiles of 32 px.
// grid (49, 32): 49 groups of 64 px (exact: 49*64 = 3136), 32 image pairs.
__global__ __launch_bounds__(256) void conv_mfma(
    const signed char* __restrict__ qa, const signed char* __restrict__ w8,
    const int* __restrict__ Qtc, const int* __restrict__ Qraw,
    const float* __restrict__ bias, const float* __restrict__ sa_p,
    const float* __restrict__ sw_p, const float* __restrict__ zp_p,
    float* __restrict__ out) {
  const int tid = threadIdx.x;
  const int lane = tid & 63;
  const int wv = tid >> 6;
  const int og = wv & 1;
  const int nsub = wv >> 1;
  const int n = blockIdx.y * 2 + nsub;
  const int p0 = blockIdx.x * 64;
  const int ln = lane & 31;
  const int lhi = lane >> 5;
  const int o = og * 32 + ln;

  // B fragments: B[n=ln][k = kk*32 + lhi*16 + j] per tap
  const signed char* wb = w8 + (size_t)o * 576 + lhi * 16;
  v4i B[9][2];
#pragma unroll
  for (int tp = 0; tp < 9; ++tp)
#pragma unroll
    for (int kk = 0; kk < 2; ++kk)
      B[tp][kk] = *(const v4i*)(wb + tp * 64 + kk * 32);

  // per-tap correction values: 128*Qtc + zp*Qraw (float)
  const float sa = sa_p[0], sw = sw_p[0], zp = zp_p[0];
  float ct[9];
#pragma unroll
  for (int k = 0; k < 9; ++k)
    ct[k] = 128.0f * (float)Qtc[o * 9 + k] + zp * (float)Qraw[o * 9 + k];
  const float Full = ct[0] + ct[1] + ct[2] + ct[3] + ct[4] + ct[5] + ct[6] + ct[7] + ct[8];
  const float Rtop = ct[0] + ct[1] + ct[2];   // removed when h == 0
  const float Rbot = ct[6] + ct[7] + ct[8];   // removed when h == 55
  const float Clft = ct[0] + ct[3] + ct[6];   // removed when w == 0
  const float Crgt = ct[2] + ct[5] + ct[8];   // removed when w == 55
  const float rden = 1.0f / (sw * sa);
  const float bo = bias[o];

  const signed char* qim = qa + (size_t)n * QA_IMG + lhi * 16;
  float* const obase = out + (size_t)(n * 64 + o) * 3136;

#pragma unroll
  for (int st = 0; st < 2; ++st) {
    const int pxa = p0 + st * 32 + ln;          // this lane's A-row pixel
    const int hp = (pxa * 9363) >> 19;          // pxa / 56 (exact for pxa < 3136)
    const int wp = pxa - hp * 56;
    const signed char* abase = qim + (hp * 58 + wp) * 64;
    v16i acc = {0, 0, 0, 0, 0, 0, 0, 0, 0, 0, 0, 0, 0, 0, 0, 0};
#pragma unroll
    for (int kh = 0; kh < 3; ++kh) {
#pragma unroll
      for (int kw = 0; kw < 3; ++kw) {
        const signed char* ap = abase + kh * QA_ROW + kw * 64;
        const v4i a0 = *(const v4i*)(ap);        // ch lhi*16 + 0..15
        const v4i a1 = *(const v4i*)(ap + 32);   // ch 32 + lhi*16 + 0..15
        acc = __builtin_amdgcn_mfma_i32_32x32x32_i8(a0, B[kh * 3 + kw][0], acc, 0, 0, 0);
        acc = __builtin_amdgcn_mfma_i32_32x32x32_i8(a1, B[kh * 3 + kw][1], acc, 0, 0, 0);
      }
    }
    // epilogue: C/D row = (reg&3) + 8*(reg>>2) + 4*lhi, col = ln
#pragma unroll
    for (int q2 = 0; q2 < 4; ++q2) {
      const int pxb = p0 + st * 32 + 8 * q2 + 4 * lhi;
      float tmp[4];
#pragma unroll
      for (int e = 0; e < 4; ++e) {
        const int p = pxb + e;
        const int h = (p * 9363) >> 19;
        const int w = p - h * 56;
        const bool tb = (h == 0), bb = (h == 55), lb = (w == 0), rb = (w == 55);
        float corr = Full;
        corr -= tb ? Rtop : 0.0f;
        corr -= bb ? Rbot : 0.0f;
        corr -= lb ? Clft : 0.0f;
        corr -= rb ? Crgt : 0.0f;
        corr += (tb && lb) ? ct[0] : 0.0f;      // corner overlaps added back
        corr += (tb && rb) ? ct[2] : 0.0f;
        corr += (bb && lb) ? ct[6] : 0.0f;
        corr += (bb && rb) ? ct[8] : 0.0f;
        tmp[e] = ((float)acc[4 * q2 + e] + corr) * rden + bo;
      }
      float4 vv;
      vv.x = tmp[0]; vv.y = tmp[1]; vv.z = tmp[2]; vv.w = tmp[3];
      *(float4*)(obase + pxb) = vv;
    }
  }
}

extern "C" void kernel_launch(void* const* d_in, const int* in_sizes, int n_in,
                              void* d_out, int out_size, void* d_ws, size_t ws_size,
                              hipStream_t stream) {
  const float* x    = (const float*)d_in[0];
  const float* wt   = (const float*)d_in[1];
  const float* bias = (const float*)d_in[2];
  const float* sa   = (const float*)d_in[3];
  const float* sw   = (const float*)d_in[4];
  const float* zp   = (const float*)d_in[5];
  float* out = (float*)d_out;

  char* ws = (char*)d_ws;
  signed char* qa = (signed char*)ws;                       // QA_BYTES
  signed char* w8 = (signed char*)(ws + QA_BYTES);          // 36,864 B
  int* Qtc  = (int*)(ws + QA_BYTES + 36864);                // 2,304 B
  int* Qraw = (int*)(ws + QA_BYTES + 36864 + 2304);         // 2,304 B

  prep_wq<<<64, 64, 0, stream>>>(wt, sw, w8, Qtc, Qraw);
  quant_a<<<dim3(28, 64), 256, 0, stream>>>(x, sa, zp, qa);
  conv_mfma<<<dim3(49, 32), 256, 0, stream>>>(qa, w8, Qtc, Qraw, bias, sa, sw, zp, out);
}